// Round 6
// baseline (1459.949 us; speedup 1.0000x reference)
//
#include <hip/hip_runtime.h>
#include <hip/hip_bf16.h>

#define N_NODES 10000
#define N_EDGES 160000

// ---------------- edge extraction (int32 expected; int64 fallback) ----------------

__global__ void k_extract(const int* __restrict__ ei,
                          int* __restrict__ row, int* __restrict__ col) {
    bool is64 = true;
#pragma unroll
    for (int i = 0; i < 8; ++i) is64 = is64 && (ei[2 * i + 1] == 0);
    int e = blockIdx.x * 256 + threadIdx.x;
    if (e < N_EDGES) {
        if (is64) {
            row[e] = ei[2 * e];
            col[e] = ei[2 * (N_EDGES + e)];
        } else {
            row[e] = ei[e];
            col[e] = ei[N_EDGES + e];
        }
    }
}

// ---------------- degree / dis ----------------

__global__ void k_deg_init(int* deg) {
    int i = blockIdx.x * 256 + threadIdx.x;
    if (i < N_NODES) deg[i] = 1;  // self-loop contribution
}

__global__ void k_deg_count(const int* __restrict__ col, int* deg) {
    int e = blockIdx.x * 256 + threadIdx.x;
    if (e < N_EDGES) atomicAdd(&deg[col[e]], 1);
}

__global__ void k_dis(const int* __restrict__ deg, float* __restrict__ dis) {
    int i = blockIdx.x * 256 + threadIdx.x;
    if (i < N_NODES) dis[i] = rsqrtf((float)deg[i]);  // deg >= 1 always
}

// ---------------- f32 GEMM (validated structure, no bias/relu): t = A @ W ----------------
// A:[M,K] f32 row-major, W:[K,NO] f32 row-major. 64x64 tile, 256 thr, 4x4/thread.

__global__ __launch_bounds__(256) void k_gemm_nb(
        const float* __restrict__ A, const float* __restrict__ W,
        float* __restrict__ out, int M, int K, int NO) {
    __shared__ float As[16][64];
    __shared__ float Bs[16][64];

    int tid = threadIdx.x;
    int tx = tid & 15;
    int ty = tid >> 4;
    int m0 = blockIdx.x * 64;
    int n0 = blockIdx.y * 64;

    int ar = tid & 63;
    int ac4 = (tid >> 6) * 4;
    int arow = m0 + ar; if (arow > M - 1) arow = M - 1;
    const float* ap = A + (size_t)arow * K + ac4;
    int bk = tid >> 4;
    int bc = tx * 4;
    const float* bp = W + (size_t)bk * NO + n0 + bc;

    float acc[4][4];
#pragma unroll
    for (int i = 0; i < 4; ++i)
#pragma unroll
        for (int j = 0; j < 4; ++j) acc[i][j] = 0.f;

    for (int k0 = 0; k0 < K; k0 += 16) {
        float4 av = *(const float4*)(ap + k0);
        float4 bv = *(const float4*)(bp + (size_t)k0 * NO);
        As[ac4 + 0][ar] = av.x;
        As[ac4 + 1][ar] = av.y;
        As[ac4 + 2][ar] = av.z;
        As[ac4 + 3][ar] = av.w;
        *(float4*)&Bs[bk][bc] = bv;
        __syncthreads();
#pragma unroll
        for (int kk = 0; kk < 16; ++kk) {
            float4 a = *(const float4*)&As[kk][ty * 4];
            float4 b = *(const float4*)&Bs[kk][tx * 4];
            float aa[4] = {a.x, a.y, a.z, a.w};
            float bb[4] = {b.x, b.y, b.z, b.w};
#pragma unroll
            for (int i = 0; i < 4; ++i)
#pragma unroll
                for (int j = 0; j < 4; ++j)
                    acc[i][j] = fmaf(aa[i], bb[j], acc[i][j]);
        }
        __syncthreads();
    }

#pragma unroll
    for (int i = 0; i < 4; ++i) {
        int r = m0 + ty * 4 + i;
        if (r < M) {
#pragma unroll
            for (int j = 0; j < 4; ++j)
                out[(size_t)r * NO + n0 + tx * 4 + j] = acc[i][j];
        }
    }
}

// ---------------- self-loop init: s[i][c] = t[i][c] * dis[i]^2 ----------------

__global__ void k_selfinit(const float* __restrict__ t, float* __restrict__ s,
                           const float* __restrict__ dis) {
    int idx = blockIdx.x * 256 + threadIdx.x;  // over N_NODES*512
    int node = idx >> 9;
    float d = dis[node];
    s[idx] = t[idx] * d * d;
}

// ---------------- literal edge scatter: s[col] += t[row] * dis[row]*dis[col] ----------------
// One wave per edge, 512 features in 8 strides of 64.

__global__ void k_scatter(const float* __restrict__ t, float* s,
                          const int* __restrict__ row, const int* __restrict__ col,
                          const float* __restrict__ dis) {
    int e = blockIdx.x * 4 + (threadIdx.x >> 6);
    int lane = threadIdx.x & 63;
    if (e >= N_EDGES) return;
    int r = row[e], c = col[e];
    float nm = dis[r] * dis[c];
    const float* tp = t + (size_t)r * 512;
    float* sp = s + (size_t)c * 512;
#pragma unroll
    for (int i = 0; i < 8; ++i)
        atomicAdd(&sp[i * 64 + lane], tp[i * 64 + lane] * nm);
}

// ---------------- epilogue: h = relu(s + b) (in-place, f32) ----------------

__global__ void k_epi(float* s, const float* __restrict__ bias) {
    int idx = blockIdx.x * 256 + threadIdx.x;
    float v = s[idx] + bias[idx & 511];
    s[idx] = fmaxf(v, 0.f);
}

// final layer: no relu, f32 store to d_out (reference output dtype is float32)
__global__ void k_epi_out(const float* __restrict__ s, const float* __restrict__ bias,
                          float* __restrict__ out) {
    int idx = blockIdx.x * 256 + threadIdx.x;
    out[idx] = s[idx] + bias[idx & 511];
}

// ---------------- launch ----------------

extern "C" void kernel_launch(void* const* d_in, const int* in_sizes, int n_in,
                              void* d_out, int out_size, void* d_ws, size_t ws_size,
                              hipStream_t stream) {
    const float* x  = (const float*)d_in[0];
    const int*   ei = (const int*)d_in[1];
    const float* W1 = (const float*)d_in[2];
    const float* b1 = (const float*)d_in[3];
    const float* W2 = (const float*)d_in[4];
    const float* b2 = (const float*)d_in[5];
    const float* W3 = (const float*)d_in[6];
    const float* b3 = (const float*)d_in[7];
    const float* W4 = (const float*)d_in[8];
    const float* b4 = (const float*)d_in[9];

    char* ws = (char*)d_ws;
    size_t o = 0;
    auto alloc = [&](size_t bytes) {
        char* p = ws + o;
        o = (o + bytes + 255) & ~(size_t)255;
        return p;
    };
    int*   row = (int*)alloc(N_EDGES * 4);
    int*   col = (int*)alloc(N_EDGES * 4);
    int*   deg = (int*)alloc(N_NODES * 4);
    float* dis = (float*)alloc(N_NODES * 4);
    float* t   = (float*)alloc((size_t)N_NODES * 512 * 4);  // gemm output
    float* s   = (float*)alloc((size_t)N_NODES * 512 * 4);  // aggregated + in-place h
    float* outb = (float*)d_out;

    dim3 b256(256);
    const int gN = (N_NODES + 255) / 256;
    const int gE = (N_EDGES + 255) / 256;
    const int gF = N_NODES * 512 / 256;   // 20000, exact
    const int gS = N_EDGES / 4;           // 40000, exact

    k_extract<<<gE, b256, 0, stream>>>(ei, row, col);
    k_deg_init<<<gN, b256, 0, stream>>>(deg);
    k_deg_count<<<gE, b256, 0, stream>>>(col, deg);
    k_dis<<<gN, b256, 0, stream>>>(deg, dis);

    // Layer 1: t = x @ W1 (K=256); s = selfloop + scatter; s = relu(s + b1)
    k_gemm_nb<<<dim3(157, 8), b256, 0, stream>>>(x, W1, t, N_NODES, 256, 512);
    k_selfinit<<<gF, b256, 0, stream>>>(t, s, dis);
    k_scatter<<<gS, b256, 0, stream>>>(t, s, row, col, dis);
    k_epi<<<gF, b256, 0, stream>>>(s, b1);
    // Layer 2
    k_gemm_nb<<<dim3(157, 8), b256, 0, stream>>>(s, W2, t, N_NODES, 512, 512);
    k_selfinit<<<gF, b256, 0, stream>>>(t, s, dis);
    k_scatter<<<gS, b256, 0, stream>>>(t, s, row, col, dis);
    k_epi<<<gF, b256, 0, stream>>>(s, b2);
    // Layer 3
    k_gemm_nb<<<dim3(157, 8), b256, 0, stream>>>(s, W3, t, N_NODES, 512, 512);
    k_selfinit<<<gF, b256, 0, stream>>>(t, s, dis);
    k_scatter<<<gS, b256, 0, stream>>>(t, s, row, col, dis);
    k_epi<<<gF, b256, 0, stream>>>(s, b3);
    // Layer 4 (no relu) -> f32 d_out
    k_gemm_nb<<<dim3(157, 8), b256, 0, stream>>>(s, W4, t, N_NODES, 512, 512);
    k_selfinit<<<gF, b256, 0, stream>>>(t, s, dis);
    k_scatter<<<gS, b256, 0, stream>>>(t, s, row, col, dis);
    k_epi_out<<<gF, b256, 0, stream>>>(s, b4, outb);
}

// Round 7
// 584.407 us; speedup vs baseline: 2.4982x; 2.4982x over previous
//
#include <hip/hip_runtime.h>
#include <hip/hip_bf16.h>

#define N_NODES 10000
#define N_EDGES 160000

// ---------------- edge extraction (int32 expected; int64 fallback) ----------------

__global__ void k_extract(const int* __restrict__ ei,
                          int* __restrict__ row, int* __restrict__ col) {
    bool is64 = true;
#pragma unroll
    for (int i = 0; i < 8; ++i) is64 = is64 && (ei[2 * i + 1] == 0);
    int e = blockIdx.x * 256 + threadIdx.x;
    if (e < N_EDGES) {
        if (is64) {
            row[e] = ei[2 * e];
            col[e] = ei[2 * (N_EDGES + e)];
        } else {
            row[e] = ei[e];
            col[e] = ei[N_EDGES + e];
        }
    }
}

// ---------------- CSR build (cross-validated vs literal scatter in r4/r5) ----------------

__global__ void k_deg_init(int* deg) {
    int i = blockIdx.x * 256 + threadIdx.x;
    if (i < N_NODES) deg[i] = 1;  // self-loop
}

__global__ void k_deg_count(const int* __restrict__ col, int* deg) {
    int e = blockIdx.x * 256 + threadIdx.x;
    if (e < N_EDGES) atomicAdd(&deg[col[e]], 1);
}

__global__ void k_dis(const int* __restrict__ deg, float* __restrict__ dis) {
    int i = blockIdx.x * 256 + threadIdx.x;
    if (i < N_NODES) dis[i] = rsqrtf((float)deg[i]);  // deg >= 1 always
}

// Single-block two-level exclusive scan of in-degree (deg-1) over 10000 nodes.
__global__ void k_scan(const int* __restrict__ deg, int* __restrict__ off) {
    __shared__ int sums[256];
    int t = threadIdx.x;
    const int seg = (N_NODES + 255) >> 8;  // 40
    int lo = t * seg;
    int hi = lo + seg;
    if (lo > N_NODES) lo = N_NODES;
    if (hi > N_NODES) hi = N_NODES;
    int s = 0;
    for (int i = lo; i < hi; ++i) s += deg[i] - 1;
    sums[t] = s;
    __syncthreads();
    for (int d = 1; d < 256; d <<= 1) {
        int v = (t >= d) ? sums[t - d] : 0;
        __syncthreads();
        sums[t] += v;
        __syncthreads();
    }
    int run = sums[t] - s;  // exclusive prefix
    for (int i = lo; i < hi; ++i) {
        off[i] = run;
        run += deg[i] - 1;
    }
    if (t == 255) off[N_NODES] = sums[255];
}

__global__ void k_cursor(const int* __restrict__ off, int* __restrict__ cur) {
    int i = blockIdx.x * 256 + threadIdx.x;
    if (i < N_NODES) cur[i] = off[i];
}

__global__ void k_fill(const int* __restrict__ row, const int* __restrict__ col,
                       const float* __restrict__ dis, int* cur,
                       int* __restrict__ crow, float* __restrict__ cnorm) {
    int e = blockIdx.x * 256 + threadIdx.x;
    if (e < N_EDGES) {
        int r = row[e], c = col[e];
        int p = atomicAdd(&cur[c], 1);
        crow[p] = r;
        cnorm[p] = dis[r] * dis[c];
    }
}

// ---------------- Aggregation by CSR GATHER: s = A_norm @ in ----------------
// One wave per (node, 256-feature chunk); float4 per lane (1 KB per row read).
// Self-loop fused: norm = dis[node]^2. No atomics; writes only N*C*4 bytes.

__global__ void k_agg(const float* __restrict__ in, float* __restrict__ out,
                      const int* __restrict__ off, const int* __restrict__ crow,
                      const float* __restrict__ cnorm, const float* __restrict__ dis,
                      int cshift) {  // C = 256 << cshift
    int wid = blockIdx.x * 4 + (threadIdx.x >> 6);
    int lane = threadIdx.x & 63;
    int node = wid >> cshift;
    if (node >= N_NODES) return;
    int ch = wid & ((1 << cshift) - 1);
    int C = 256 << cshift;
    int c = ch * 256 + lane * 4;

    float d = dis[node];
    float4 acc = *(const float4*)(in + (size_t)node * C + c);
    acc.x *= d * d; acc.y *= d * d; acc.z *= d * d; acc.w *= d * d;

    int b = off[node], e = off[node + 1];
    for (int i = b; i < e; ++i) {
        int r = crow[i];
        float nm = cnorm[i];
        float4 v = *(const float4*)(in + (size_t)r * C + c);
        acc.x = fmaf(v.x, nm, acc.x);
        acc.y = fmaf(v.y, nm, acc.y);
        acc.z = fmaf(v.z, nm, acc.z);
        acc.w = fmaf(v.w, nm, acc.w);
    }
    *(float4*)(out + (size_t)node * C + c) = acc;
}

// ---------------- f32 GEMM with fused bias(+relu): out = act(A @ W + b) ----------------
// A:[M,K] f32 row-major, W:[K,NO] f32 row-major. 64x64 tile, 256 thr, 4x4/thread.
// Validated structure (r4/r5/r6). A-row loads clamped to M-1 (feed guarded stores).

__global__ __launch_bounds__(256) void k_gemm(
        const float* __restrict__ A, const float* __restrict__ W,
        const float* __restrict__ bias, float* __restrict__ out,
        int M, int K, int NO, int relu) {
    __shared__ float As[16][64];
    __shared__ float Bs[16][64];

    int tid = threadIdx.x;
    int tx = tid & 15;
    int ty = tid >> 4;
    int m0 = blockIdx.x * 64;
    int n0 = blockIdx.y * 64;

    int ar = tid & 63;
    int ac4 = (tid >> 6) * 4;
    int arow = m0 + ar; if (arow > M - 1) arow = M - 1;
    const float* ap = A + (size_t)arow * K + ac4;
    int bk = tid >> 4;
    int bc = tx * 4;
    const float* bp = W + (size_t)bk * NO + n0 + bc;

    float acc[4][4];
#pragma unroll
    for (int i = 0; i < 4; ++i)
#pragma unroll
        for (int j = 0; j < 4; ++j) acc[i][j] = 0.f;

    for (int k0 = 0; k0 < K; k0 += 16) {
        float4 av = *(const float4*)(ap + k0);
        float4 bv = *(const float4*)(bp + (size_t)k0 * NO);
        As[ac4 + 0][ar] = av.x;
        As[ac4 + 1][ar] = av.y;
        As[ac4 + 2][ar] = av.z;
        As[ac4 + 3][ar] = av.w;
        *(float4*)&Bs[bk][bc] = bv;
        __syncthreads();
#pragma unroll
        for (int kk = 0; kk < 16; ++kk) {
            float4 a = *(const float4*)&As[kk][ty * 4];
            float4 b = *(const float4*)&Bs[kk][tx * 4];
            float aa[4] = {a.x, a.y, a.z, a.w};
            float bb[4] = {b.x, b.y, b.z, b.w};
#pragma unroll
            for (int i = 0; i < 4; ++i)
#pragma unroll
                for (int j = 0; j < 4; ++j)
                    acc[i][j] = fmaf(aa[i], bb[j], acc[i][j]);
        }
        __syncthreads();
    }

    float bv4[4];
#pragma unroll
    for (int j = 0; j < 4; ++j) bv4[j] = bias[n0 + tx * 4 + j];
#pragma unroll
    for (int i = 0; i < 4; ++i) {
        int r = m0 + ty * 4 + i;
        if (r < M) {
#pragma unroll
            for (int j = 0; j < 4; ++j) {
                float v = acc[i][j] + bv4[j];
                if (relu) v = fmaxf(v, 0.f);
                out[(size_t)r * NO + n0 + tx * 4 + j] = v;
            }
        }
    }
}

// ---------------- launch ----------------

extern "C" void kernel_launch(void* const* d_in, const int* in_sizes, int n_in,
                              void* d_out, int out_size, void* d_ws, size_t ws_size,
                              hipStream_t stream) {
    const float* x  = (const float*)d_in[0];
    const int*   ei = (const int*)d_in[1];
    const float* W1 = (const float*)d_in[2];
    const float* b1 = (const float*)d_in[3];
    const float* W2 = (const float*)d_in[4];
    const float* b2 = (const float*)d_in[5];
    const float* W3 = (const float*)d_in[6];
    const float* b3 = (const float*)d_in[7];
    const float* W4 = (const float*)d_in[8];
    const float* b4 = (const float*)d_in[9];

    char* ws = (char*)d_ws;
    size_t o = 0;
    auto alloc = [&](size_t bytes) {
        char* p = ws + o;
        o = (o + bytes + 255) & ~(size_t)255;
        return p;
    };
    int*   row   = (int*)alloc(N_EDGES * 4);
    int*   col   = (int*)alloc(N_EDGES * 4);
    int*   deg   = (int*)alloc(N_NODES * 4);
    float* dis   = (float*)alloc(N_NODES * 4);
    int*   off   = (int*)alloc((N_NODES + 1) * 4);
    int*   cur   = (int*)alloc(N_NODES * 4);
    int*   crow  = (int*)alloc(N_EDGES * 4);
    float* cnorm = (float*)alloc(N_EDGES * 4);
    float* s     = (float*)alloc((size_t)N_NODES * 512 * 4);  // aggregated features
    float* h     = (float*)alloc((size_t)N_NODES * 512 * 4);  // hidden state
    float* outb  = (float*)d_out;

    dim3 b256(256);
    const int gN = (N_NODES + 255) / 256;
    const int gE = (N_EDGES + 255) / 256;

    k_extract<<<gE, b256, 0, stream>>>(ei, row, col);
    k_deg_init<<<gN, b256, 0, stream>>>(deg);
    k_deg_count<<<gE, b256, 0, stream>>>(col, deg);
    k_dis<<<gN, b256, 0, stream>>>(deg, dis);
    k_scan<<<1, b256, 0, stream>>>(deg, off);
    k_cursor<<<gN, b256, 0, stream>>>(off, cur);
    k_fill<<<gE, b256, 0, stream>>>(row, col, dis, cur, crow, cnorm);

    // Layer 1: s = A_norm @ x (C=256, 1 chunk/node), h = relu(s @ W1 + b1)
    k_agg<<<N_NODES * 1 / 4, b256, 0, stream>>>(x, s, off, crow, cnorm, dis, 0);
    k_gemm<<<dim3(157, 8), b256, 0, stream>>>(s, W1, b1, h, N_NODES, 256, 512, 1);
    // Layer 2: s = A_norm @ h (C=512, 2 chunks/node), h = relu(s @ W2 + b2)
    k_agg<<<N_NODES * 2 / 4, b256, 0, stream>>>(h, s, off, crow, cnorm, dis, 1);
    k_gemm<<<dim3(157, 8), b256, 0, stream>>>(s, W2, b2, h, N_NODES, 512, 512, 1);
    // Layer 3
    k_agg<<<N_NODES * 2 / 4, b256, 0, stream>>>(h, s, off, crow, cnorm, dis, 1);
    k_gemm<<<dim3(157, 8), b256, 0, stream>>>(s, W3, b3, h, N_NODES, 512, 512, 1);
    // Layer 4 (no relu) -> f32 d_out
    k_agg<<<N_NODES * 2 / 4, b256, 0, stream>>>(h, s, off, crow, cnorm, dis, 1);
    k_gemm<<<dim3(157, 8), b256, 0, stream>>>(s, W4, b4, outb, N_NODES, 512, 512, 0);
}

// Round 8
// 576.588 us; speedup vs baseline: 2.5320x; 1.0136x over previous
//
#include <hip/hip_runtime.h>
#include <hip/hip_bf16.h>

#define N_NODES 10000
#define N_EDGES 160000

// ---------------- edge extraction (int32 expected; int64 fallback) ----------------

__global__ void k_extract(const int* __restrict__ ei,
                          int* __restrict__ row, int* __restrict__ col) {
    bool is64 = true;
#pragma unroll
    for (int i = 0; i < 8; ++i) is64 = is64 && (ei[2 * i + 1] == 0);
    int e = blockIdx.x * 256 + threadIdx.x;
    if (e < N_EDGES) {
        if (is64) {
            row[e] = ei[2 * e];
            col[e] = ei[2 * (N_EDGES + e)];
        } else {
            row[e] = ei[e];
            col[e] = ei[N_EDGES + e];
        }
    }
}

// ---------------- CSR build (cross-validated vs literal scatter r4/r5) ----------------

__global__ void k_deg_init(int* deg) {
    int i = blockIdx.x * 256 + threadIdx.x;
    if (i < N_NODES) deg[i] = 1;  // self-loop
}

__global__ void k_deg_count(const int* __restrict__ col, int* deg) {
    int e = blockIdx.x * 256 + threadIdx.x;
    if (e < N_EDGES) atomicAdd(&deg[col[e]], 1);
}

__global__ void k_dis(const int* __restrict__ deg, float* __restrict__ dis) {
    int i = blockIdx.x * 256 + threadIdx.x;
    if (i < N_NODES) dis[i] = rsqrtf((float)deg[i]);
}

__global__ void k_scan(const int* __restrict__ deg, int* __restrict__ off) {
    __shared__ int sums[256];
    int t = threadIdx.x;
    const int seg = (N_NODES + 255) >> 8;
    int lo = t * seg;
    int hi = lo + seg;
    if (lo > N_NODES) lo = N_NODES;
    if (hi > N_NODES) hi = N_NODES;
    int s = 0;
    for (int i = lo; i < hi; ++i) s += deg[i] - 1;
    sums[t] = s;
    __syncthreads();
    for (int d = 1; d < 256; d <<= 1) {
        int v = (t >= d) ? sums[t - d] : 0;
        __syncthreads();
        sums[t] += v;
        __syncthreads();
    }
    int run = sums[t] - s;
    for (int i = lo; i < hi; ++i) {
        off[i] = run;
        run += deg[i] - 1;
    }
    if (t == 255) off[N_NODES] = sums[255];
}

__global__ void k_cursor(const int* __restrict__ off, int* __restrict__ cur) {
    int i = blockIdx.x * 256 + threadIdx.x;
    if (i < N_NODES) cur[i] = off[i];
}

__global__ void k_fill(const int* __restrict__ row, const int* __restrict__ col,
                       const float* __restrict__ dis, int* cur,
                       int* __restrict__ crow, float* __restrict__ cnorm) {
    int e = blockIdx.x * 256 + threadIdx.x;
    if (e < N_EDGES) {
        int r = row[e], c = col[e];
        int p = atomicAdd(&cur[c], 1);
        crow[p] = r;
        cnorm[p] = dis[r] * dis[c];
    }
}

// ---------------- Aggregation by CSR gather: s = A_norm @ in ----------------
// One wave per (node, 256-feature chunk); float4/lane. 2-way unrolled edge loop
// with dual accumulators for load-level parallelism. Self-loop fused.

__global__ void k_agg(const float* __restrict__ in, float* __restrict__ out,
                      const int* __restrict__ off, const int* __restrict__ crow,
                      const float* __restrict__ cnorm, const float* __restrict__ dis,
                      int cshift) {  // C = 256 << cshift
    int wid = blockIdx.x * 4 + (threadIdx.x >> 6);
    int lane = threadIdx.x & 63;
    int node = wid >> cshift;
    if (node >= N_NODES) return;
    int ch = wid & ((1 << cshift) - 1);
    int C = 256 << cshift;
    int c = ch * 256 + lane * 4;

    float d = dis[node];
    float4 acc = *(const float4*)(in + (size_t)node * C + c);
    acc.x *= d * d; acc.y *= d * d; acc.z *= d * d; acc.w *= d * d;
    float4 acc2 = {0.f, 0.f, 0.f, 0.f};

    int b = off[node], e = off[node + 1];
    int i = b;
    for (; i + 1 < e; i += 2) {
        int r0 = crow[i], r1 = crow[i + 1];
        float n0 = cnorm[i], n1 = cnorm[i + 1];
        float4 v0 = *(const float4*)(in + (size_t)r0 * C + c);
        float4 v1 = *(const float4*)(in + (size_t)r1 * C + c);
        acc.x = fmaf(v0.x, n0, acc.x);  acc2.x = fmaf(v1.x, n1, acc2.x);
        acc.y = fmaf(v0.y, n0, acc.y);  acc2.y = fmaf(v1.y, n1, acc2.y);
        acc.z = fmaf(v0.z, n0, acc.z);  acc2.z = fmaf(v1.z, n1, acc2.z);
        acc.w = fmaf(v0.w, n0, acc.w);  acc2.w = fmaf(v1.w, n1, acc2.w);
    }
    if (i < e) {
        int r0 = crow[i];
        float n0 = cnorm[i];
        float4 v0 = *(const float4*)(in + (size_t)r0 * C + c);
        acc.x = fmaf(v0.x, n0, acc.x);
        acc.y = fmaf(v0.y, n0, acc.y);
        acc.z = fmaf(v0.z, n0, acc.z);
        acc.w = fmaf(v0.w, n0, acc.w);
    }
    acc.x += acc2.x; acc.y += acc2.y; acc.z += acc2.z; acc.w += acc2.w;
    *(float4*)(out + (size_t)node * C + c) = acc;
}

// ---------------- f32 GEMM, 128x64 tile, 8x4 regs/thread, fused bias(+relu) ----------
// A:[M,K] f32 row-major, W:[K,NO] f32 row-major. 256 threads. BK=16.
// A-row loads clamped to M-1 (feed only store-guarded rows).

__global__ __launch_bounds__(256) void k_gemm(
        const float* __restrict__ A, const float* __restrict__ W,
        const float* __restrict__ bias, float* __restrict__ out,
        int M, int K, int NO, int relu) {
    __shared__ float As[16][128];  // [k][m]
    __shared__ float Bs[16][64];   // [k][n]

    int tid = threadIdx.x;
    int tx = tid & 15;        // n-subtile: 4 cols
    int ty = tid >> 4;        // m-subtile: 8 rows (0..15)
    int m0 = blockIdx.x * 128;
    int n0 = blockIdx.y * 64;

    // A loads: 128 rows x 16 k = 2048 floats = 2 float4/thread
    int ar = tid & 127;
    int ak = (tid >> 7) * 4;  // 0 or 4; plus +8 for the second float4
    int arow = m0 + ar; if (arow > M - 1) arow = M - 1;
    const float* ap = A + (size_t)arow * K + ak;
    // B loads: 16 rows x 64 cols = 1024 floats = 1 float4/thread
    int bk = tid >> 4;
    int bc = tx * 4;
    const float* bp = W + (size_t)bk * NO + n0 + bc;

    float acc[8][4];
#pragma unroll
    for (int i = 0; i < 8; ++i)
#pragma unroll
        for (int j = 0; j < 4; ++j) acc[i][j] = 0.f;

    for (int k0 = 0; k0 < K; k0 += 16) {
        float4 av0 = *(const float4*)(ap + k0);
        float4 av1 = *(const float4*)(ap + k0 + 8);
        float4 bv = *(const float4*)(bp + (size_t)k0 * NO);
        As[ak + 0][ar] = av0.x;
        As[ak + 1][ar] = av0.y;
        As[ak + 2][ar] = av0.z;
        As[ak + 3][ar] = av0.w;
        As[ak + 8][ar] = av1.x;
        As[ak + 9][ar] = av1.y;
        As[ak + 10][ar] = av1.z;
        As[ak + 11][ar] = av1.w;
        *(float4*)&Bs[bk][bc] = bv;
        __syncthreads();
#pragma unroll
        for (int kk = 0; kk < 16; ++kk) {
            float4 a0 = *(const float4*)&As[kk][ty * 8];
            float4 a1 = *(const float4*)&As[kk][ty * 8 + 4];
            float4 b = *(const float4*)&Bs[kk][tx * 4];
            float aa[8] = {a0.x, a0.y, a0.z, a0.w, a1.x, a1.y, a1.z, a1.w};
            float bb[4] = {b.x, b.y, b.z, b.w};
#pragma unroll
            for (int i = 0; i < 8; ++i)
#pragma unroll
                for (int j = 0; j < 4; ++j)
                    acc[i][j] = fmaf(aa[i], bb[j], acc[i][j]);
        }
        __syncthreads();
    }

    float bv4[4];
#pragma unroll
    for (int j = 0; j < 4; ++j) bv4[j] = bias[n0 + tx * 4 + j];
#pragma unroll
    for (int i = 0; i < 8; ++i) {
        int r = m0 + ty * 8 + i;
        if (r < M) {
#pragma unroll
            for (int j = 0; j < 4; ++j) {
                float v = acc[i][j] + bv4[j];
                if (relu) v = fmaxf(v, 0.f);
                out[(size_t)r * NO + n0 + tx * 4 + j] = v;
            }
        }
    }
}

// ---------------- launch ----------------

extern "C" void kernel_launch(void* const* d_in, const int* in_sizes, int n_in,
                              void* d_out, int out_size, void* d_ws, size_t ws_size,
                              hipStream_t stream) {
    const float* x  = (const float*)d_in[0];
    const int*   ei = (const int*)d_in[1];
    const float* W1 = (const float*)d_in[2];
    const float* b1 = (const float*)d_in[3];
    const float* W2 = (const float*)d_in[4];
    const float* b2 = (const float*)d_in[5];
    const float* W3 = (const float*)d_in[6];
    const float* b3 = (const float*)d_in[7];
    const float* W4 = (const float*)d_in[8];
    const float* b4 = (const float*)d_in[9];

    char* ws = (char*)d_ws;
    size_t o = 0;
    auto alloc = [&](size_t bytes) {
        char* p = ws + o;
        o = (o + bytes + 255) & ~(size_t)255;
        return p;
    };
    int*   row   = (int*)alloc(N_EDGES * 4);
    int*   col   = (int*)alloc(N_EDGES * 4);
    int*   deg   = (int*)alloc(N_NODES * 4);
    float* dis   = (float*)alloc(N_NODES * 4);
    int*   off   = (int*)alloc((N_NODES + 1) * 4);
    int*   cur   = (int*)alloc(N_NODES * 4);
    int*   crow  = (int*)alloc(N_EDGES * 4);
    float* cnorm = (float*)alloc(N_EDGES * 4);
    float* s     = (float*)alloc((size_t)N_NODES * 512 * 4);
    float* h     = (float*)alloc((size_t)N_NODES * 512 * 4);
    float* outb  = (float*)d_out;

    dim3 b256(256);
    const int gN = (N_NODES + 255) / 256;
    const int gE = (N_EDGES + 255) / 256;
    const dim3 gG(79, 8);  // ceil(10000/128) x 512/64

    k_extract<<<gE, b256, 0, stream>>>(ei, row, col);
    k_deg_init<<<gN, b256, 0, stream>>>(deg);
    k_deg_count<<<gE, b256, 0, stream>>>(col, deg);
    k_dis<<<gN, b256, 0, stream>>>(deg, dis);
    k_scan<<<1, b256, 0, stream>>>(deg, off);
    k_cursor<<<gN, b256, 0, stream>>>(off, cur);
    k_fill<<<gE, b256, 0, stream>>>(row, col, dis, cur, crow, cnorm);

    // Layer 1: s = A_norm @ x (C=256), h = relu(s @ W1 + b1)
    k_agg<<<N_NODES * 1 / 4, b256, 0, stream>>>(x, s, off, crow, cnorm, dis, 0);
    k_gemm<<<gG, b256, 0, stream>>>(s, W1, b1, h, N_NODES, 256, 512, 1);
    // Layer 2
    k_agg<<<N_NODES * 2 / 4, b256, 0, stream>>>(h, s, off, crow, cnorm, dis, 1);
    k_gemm<<<gG, b256, 0, stream>>>(s, W2, b2, h, N_NODES, 512, 512, 1);
    // Layer 3
    k_agg<<<N_NODES * 2 / 4, b256, 0, stream>>>(h, s, off, crow, cnorm, dis, 1);
    k_gemm<<<gG, b256, 0, stream>>>(s, W3, b3, h, N_NODES, 512, 512, 1);
    // Layer 4 (no relu) -> f32 d_out
    k_agg<<<N_NODES * 2 / 4, b256, 0, stream>>>(h, s, off, crow, cnorm, dis, 1);
    k_gemm<<<gG, b256, 0, stream>>>(s, W4, b4, outb, N_NODES, 512, 512, 0);
}

// Round 9
// 432.857 us; speedup vs baseline: 3.3728x; 1.3321x over previous
//
#include <hip/hip_runtime.h>
#include <hip/hip_bf16.h>

#define N_NODES 10000
#define N_EDGES 160000

typedef __hip_bfloat16 bf16;
typedef float f32x4 __attribute__((ext_vector_type(4)));
typedef short s16x8 __attribute__((ext_vector_type(8)));

static __device__ __forceinline__ unsigned short bfbits(float f) {
    bf16 b = __float2bfloat16(f);
    return *reinterpret_cast<unsigned short*>(&b);
}

// ---------------- edge extraction (int32 expected; int64 fallback) ----------------

__global__ void k_extract(const int* __restrict__ ei,
                          int* __restrict__ row, int* __restrict__ col) {
    bool is64 = true;
#pragma unroll
    for (int i = 0; i < 8; ++i) is64 = is64 && (ei[2 * i + 1] == 0);
    int e = blockIdx.x * 256 + threadIdx.x;
    if (e < N_EDGES) {
        if (is64) {
            row[e] = ei[2 * e];
            col[e] = ei[2 * (N_EDGES + e)];
        } else {
            row[e] = ei[e];
            col[e] = ei[N_EDGES + e];
        }
    }
}

// ---------------- CSR build (cross-validated vs literal scatter r4/r5) ----------------

__global__ void k_deg_init(int* deg) {
    int i = blockIdx.x * 256 + threadIdx.x;
    if (i < N_NODES) deg[i] = 1;  // self-loop
}

__global__ void k_deg_count(const int* __restrict__ col, int* deg) {
    int e = blockIdx.x * 256 + threadIdx.x;
    if (e < N_EDGES) atomicAdd(&deg[col[e]], 1);
}

__global__ void k_dis(const int* __restrict__ deg, float* __restrict__ dis) {
    int i = blockIdx.x * 256 + threadIdx.x;
    if (i < N_NODES) dis[i] = rsqrtf((float)deg[i]);
}

__global__ void k_scan(const int* __restrict__ deg, int* __restrict__ off) {
    __shared__ int sums[256];
    int t = threadIdx.x;
    const int seg = (N_NODES + 255) >> 8;
    int lo = t * seg;
    int hi = lo + seg;
    if (lo > N_NODES) lo = N_NODES;
    if (hi > N_NODES) hi = N_NODES;
    int s = 0;
    for (int i = lo; i < hi; ++i) s += deg[i] - 1;
    sums[t] = s;
    __syncthreads();
    for (int d = 1; d < 256; d <<= 1) {
        int v = (t >= d) ? sums[t - d] : 0;
        __syncthreads();
        sums[t] += v;
        __syncthreads();
    }
    int run = sums[t] - s;
    for (int i = lo; i < hi; ++i) {
        off[i] = run;
        run += deg[i] - 1;
    }
    if (t == 255) off[N_NODES] = sums[255];
}

__global__ void k_cursor(const int* __restrict__ off, int* __restrict__ cur) {
    int i = blockIdx.x * 256 + threadIdx.x;
    if (i < N_NODES) cur[i] = off[i];
}

__global__ void k_fill(const int* __restrict__ row, const int* __restrict__ col,
                       const float* __restrict__ dis, int* cur,
                       int* __restrict__ crow, float* __restrict__ cnorm) {
    int e = blockIdx.x * 256 + threadIdx.x;
    if (e < N_EDGES) {
        int r = row[e], c = col[e];
        int p = atomicAdd(&cur[c], 1);
        crow[p] = r;
        cnorm[p] = dis[r] * dis[c];
    }
}

// ---------------- W transpose + f32->bf16: WT[n][k] = bf16(W[k][n]) ----------------

__global__ void k_transpose(const float* __restrict__ W, bf16* __restrict__ WT,
                            int K, int NO) {
    __shared__ bf16 tile[32][33];
    int n0 = blockIdx.x * 32, k0 = blockIdx.y * 32;
    int tx = threadIdx.x, ty = threadIdx.y;  // block (32,8)
    for (int i = 0; i < 32; i += 8)
        tile[ty + i][tx] = __float2bfloat16(W[(size_t)(k0 + ty + i) * NO + n0 + tx]);
    __syncthreads();
    for (int i = 0; i < 32; i += 8)
        WT[(size_t)(n0 + ty + i) * K + k0 + tx] = tile[tx][ty + i];
}

// ---------------- Aggregation by CSR gather (f32 accumulate, bf16 store) ----------
// One wave per (node, 256-feature chunk); float4/lane; 2-way unrolled edge loop.
// Self-loop fused (norm = dis^2). Output s is bf16 (GEMM A operand).

__global__ void k_agg(const float* __restrict__ in, unsigned short* __restrict__ out,
                      const int* __restrict__ off, const int* __restrict__ crow,
                      const float* __restrict__ cnorm, const float* __restrict__ dis,
                      int cshift) {  // C = 256 << cshift
    int wid = blockIdx.x * 4 + (threadIdx.x >> 6);
    int lane = threadIdx.x & 63;
    int node = wid >> cshift;
    if (node >= N_NODES) return;
    int ch = wid & ((1 << cshift) - 1);
    int C = 256 << cshift;
    int c = ch * 256 + lane * 4;

    float d = dis[node];
    float4 acc = *(const float4*)(in + (size_t)node * C + c);
    acc.x *= d * d; acc.y *= d * d; acc.z *= d * d; acc.w *= d * d;
    float4 acc2 = {0.f, 0.f, 0.f, 0.f};

    int b = off[node], e = off[node + 1];
    int i = b;
    for (; i + 1 < e; i += 2) {
        int r0 = crow[i], r1 = crow[i + 1];
        float n0 = cnorm[i], n1 = cnorm[i + 1];
        float4 v0 = *(const float4*)(in + (size_t)r0 * C + c);
        float4 v1 = *(const float4*)(in + (size_t)r1 * C + c);
        acc.x = fmaf(v0.x, n0, acc.x);  acc2.x = fmaf(v1.x, n1, acc2.x);
        acc.y = fmaf(v0.y, n0, acc.y);  acc2.y = fmaf(v1.y, n1, acc2.y);
        acc.z = fmaf(v0.z, n0, acc.z);  acc2.z = fmaf(v1.z, n1, acc2.z);
        acc.w = fmaf(v0.w, n0, acc.w);  acc2.w = fmaf(v1.w, n1, acc2.w);
    }
    if (i < e) {
        int r0 = crow[i];
        float n0 = cnorm[i];
        float4 v0 = *(const float4*)(in + (size_t)r0 * C + c);
        acc.x = fmaf(v0.x, n0, acc.x);
        acc.y = fmaf(v0.y, n0, acc.y);
        acc.z = fmaf(v0.z, n0, acc.z);
        acc.w = fmaf(v0.w, n0, acc.w);
    }
    ushort4 st;
    st.x = bfbits(acc.x + acc2.x);
    st.y = bfbits(acc.y + acc2.y);
    st.z = bfbits(acc.z + acc2.z);
    st.w = bfbits(acc.w + acc2.w);
    *(ushort4*)(out + (size_t)node * C + c) = st;
}

// ---------------- bf16 MFMA GEMM: out = act(A @ W + b), f32 out ----------------
// A:[M,K] bf16 row-major (agg output), BT:[NO,K] bf16, bias f32, out f32.
// 64x64 block tile, 4 waves 2x2, each wave 32x32 via 2x2 mfma 16x16x32_bf16.
// Direct global fragment loads (LLC-resident operands). A rows clamped to M-1.

__global__ __launch_bounds__(256) void k_gemm(
        const unsigned short* __restrict__ A, const bf16* __restrict__ BT,
        const float* __restrict__ bias, float* __restrict__ out,
        int M, int K, int NO, int relu) {
    int w = threadIdx.x >> 6;
    int lane = threadIdx.x & 63;
    int wm = w >> 1, wn = w & 1;
    int m0 = blockIdx.x * 64 + wm * 32;
    int n0 = blockIdx.y * 64 + wn * 32;
    int l15 = lane & 15;
    int kq = (lane >> 4) * 8;

    int ra0 = m0 + l15;       if (ra0 > M - 1) ra0 = M - 1;
    int ra1 = m0 + 16 + l15;  if (ra1 > M - 1) ra1 = M - 1;

    const unsigned short* a0p = A + (size_t)ra0 * K + kq;
    const unsigned short* a1p = A + (size_t)ra1 * K + kq;
    const unsigned short* b0p = (const unsigned short*)BT + (size_t)(n0 + l15) * K + kq;
    const unsigned short* b1p = b0p + (size_t)16 * K;

    f32x4 acc00 = {0.f, 0.f, 0.f, 0.f};
    f32x4 acc01 = acc00, acc10 = acc00, acc11 = acc00;

    for (int k = 0; k < K; k += 32) {
        s16x8 a0 = *(const s16x8*)(a0p + k);
        s16x8 a1 = *(const s16x8*)(a1p + k);
        s16x8 b0 = *(const s16x8*)(b0p + k);
        s16x8 b1 = *(const s16x8*)(b1p + k);
        acc00 = __builtin_amdgcn_mfma_f32_16x16x32_bf16(a0, b0, acc00, 0, 0, 0);
        acc01 = __builtin_amdgcn_mfma_f32_16x16x32_bf16(a0, b1, acc01, 0, 0, 0);
        acc10 = __builtin_amdgcn_mfma_f32_16x16x32_bf16(a1, b0, acc10, 0, 0, 0);
        acc11 = __builtin_amdgcn_mfma_f32_16x16x32_bf16(a1, b1, acc11, 0, 0, 0);
    }

    // C/D layout: col = lane&15, row = (lane>>4)*4 + r   [m89-verified]
    int r0 = (lane >> 4) * 4;
    float bv0 = bias[n0 + l15];
    float bv1 = bias[n0 + 16 + l15];
#pragma unroll
    for (int r = 0; r < 4; ++r) {
        int row = m0 + r0 + r;
        if (row < M) {
            float v = acc00[r] + bv0;
            if (relu) v = fmaxf(v, 0.f);
            out[(size_t)row * NO + n0 + l15] = v;
            v = acc01[r] + bv1;
            if (relu) v = fmaxf(v, 0.f);
            out[(size_t)row * NO + n0 + 16 + l15] = v;
        }
        int row2 = row + 16;
        if (row2 < M) {
            float v = acc10[r] + bv0;
            if (relu) v = fmaxf(v, 0.f);
            out[(size_t)row2 * NO + n0 + l15] = v;
            v = acc11[r] + bv1;
            if (relu) v = fmaxf(v, 0.f);
            out[(size_t)row2 * NO + n0 + 16 + l15] = v;
        }
    }
}

// ---------------- launch ----------------

extern "C" void kernel_launch(void* const* d_in, const int* in_sizes, int n_in,
                              void* d_out, int out_size, void* d_ws, size_t ws_size,
                              hipStream_t stream) {
    const float* x  = (const float*)d_in[0];
    const int*   ei = (const int*)d_in[1];
    const float* W1 = (const float*)d_in[2];
    const float* b1 = (const float*)d_in[3];
    const float* W2 = (const float*)d_in[4];
    const float* b2 = (const float*)d_in[5];
    const float* W3 = (const float*)d_in[6];
    const float* b3 = (const float*)d_in[7];
    const float* W4 = (const float*)d_in[8];
    const float* b4 = (const float*)d_in[9];

    char* ws = (char*)d_ws;
    size_t o = 0;
    auto alloc = [&](size_t bytes) {
        char* p = ws + o;
        o = (o + bytes + 255) & ~(size_t)255;
        return p;
    };
    int*   row   = (int*)alloc(N_EDGES * 4);
    int*   col   = (int*)alloc(N_EDGES * 4);
    int*   deg   = (int*)alloc(N_NODES * 4);
    float* dis   = (float*)alloc(N_NODES * 4);
    int*   off   = (int*)alloc((N_NODES + 1) * 4);
    int*   cur   = (int*)alloc(N_NODES * 4);
    int*   crow  = (int*)alloc(N_EDGES * 4);
    float* cnorm = (float*)alloc(N_EDGES * 4);
    bf16*  WT1   = (bf16*)alloc((size_t)512 * 256 * 2);
    bf16*  WT2   = (bf16*)alloc((size_t)512 * 512 * 2);
    bf16*  WT3   = (bf16*)alloc((size_t)512 * 512 * 2);
    bf16*  WT4   = (bf16*)alloc((size_t)512 * 512 * 2);
    unsigned short* s = (unsigned short*)alloc((size_t)N_NODES * 512 * 2);  // bf16 agg
    float* h     = (float*)alloc((size_t)N_NODES * 512 * 4);                // f32 hidden
    float* outb  = (float*)d_out;

    dim3 b256(256);
    const int gN = (N_NODES + 255) / 256;
    const int gE = (N_EDGES + 255) / 256;
    const dim3 gG(157, 8);  // ceil(10000/64) x 512/64

    k_extract<<<gE, b256, 0, stream>>>(ei, row, col);
    k_deg_init<<<gN, b256, 0, stream>>>(deg);
    k_deg_count<<<gE, b256, 0, stream>>>(col, deg);
    k_dis<<<gN, b256, 0, stream>>>(deg, dis);
    k_scan<<<1, b256, 0, stream>>>(deg, off);
    k_cursor<<<gN, b256, 0, stream>>>(off, cur);
    k_fill<<<gE, b256, 0, stream>>>(row, col, dis, cur, crow, cnorm);

    k_transpose<<<dim3(16, 8),  dim3(32, 8), 0, stream>>>(W1, WT1, 256, 512);
    k_transpose<<<dim3(16, 16), dim3(32, 8), 0, stream>>>(W2, WT2, 512, 512);
    k_transpose<<<dim3(16, 16), dim3(32, 8), 0, stream>>>(W3, WT3, 512, 512);
    k_transpose<<<dim3(16, 16), dim3(32, 8), 0, stream>>>(W4, WT4, 512, 512);

    // Layer 1: s = bf16(A_norm @ x) (C=256), h = relu(s @ W1 + b1)  [f32 out]
    k_agg<<<N_NODES * 1 / 4, b256, 0, stream>>>(x, s, off, crow, cnorm, dis, 0);
    k_gemm<<<gG, b256, 0, stream>>>(s, WT1, b1, h, N_NODES, 256, 512, 1);
    // Layer 2
    k_agg<<<N_NODES * 2 / 4, b256, 0, stream>>>(h, s, off, crow, cnorm, dis, 1);
    k_gemm<<<gG, b256, 0, stream>>>(s, WT2, b2, h, N_NODES, 512, 512, 1);
    // Layer 3
    k_agg<<<N_NODES * 2 / 4, b256, 0, stream>>>(h, s, off, crow, cnorm, dis, 1);
    k_gemm<<<gG, b256, 0, stream>>>(s, WT3, b3, h, N_NODES, 512, 512, 1);
    // Layer 4 (no relu) -> f32 d_out
    k_agg<<<N_NODES * 2 / 4, b256, 0, stream>>>(h, s, off, crow, cnorm, dis, 1);
    k_gemm<<<gG, b256, 0, stream>>>(s, WT4, b4, outb, N_NODES, 512, 512, 0);
}

// Round 10
// 376.475 us; speedup vs baseline: 3.8779x; 1.1498x over previous
//
#include <hip/hip_runtime.h>
#include <hip/hip_bf16.h>

#define N_NODES 10000
#define N_EDGES 160000

typedef __hip_bfloat16 bf16;
typedef unsigned short u16;
typedef float f32x4 __attribute__((ext_vector_type(4)));
typedef short s16x8 __attribute__((ext_vector_type(8)));
typedef unsigned short us8 __attribute__((ext_vector_type(8)));
typedef unsigned short us4 __attribute__((ext_vector_type(4)));

static __device__ __forceinline__ float b2f(u16 u) {
    unsigned v = (unsigned)u << 16;
    return __uint_as_float(v);
}
static __device__ __forceinline__ u16 f2b(float f) {
    bf16 b = __float2bfloat16(f);
    return *reinterpret_cast<u16*>(&b);
}

// ---------------- prep 0: zero deg + extract edges (int32/int64 robust) ----------

__global__ void k_prep0(const int* __restrict__ ei,
                        int* __restrict__ row, int* __restrict__ col,
                        int* __restrict__ deg) {
    bool is64 = true;
#pragma unroll
    for (int i = 0; i < 8; ++i) is64 = is64 && (ei[2 * i + 1] == 0);
    int t = blockIdx.x * 256 + threadIdx.x;
    if (t < N_NODES) deg[t] = 0;  // raw in-degree (self-loop added later as +1)
    if (t < N_EDGES) {
        if (is64) {
            row[t] = ei[2 * t];
            col[t] = ei[2 * (N_EDGES + t)];
        } else {
            row[t] = ei[t];
            col[t] = ei[N_EDGES + t];
        }
    }
}

__global__ void k_count(const int* __restrict__ col, int* deg) {
    int e = blockIdx.x * 256 + threadIdx.x;
    if (e < N_EDGES) atomicAdd(&deg[col[e]], 1);
}

// Single block: dis = rsqrt(deg+1); exclusive scan of deg -> off, cur.
__global__ void k_scan_all(const int* __restrict__ deg, float* __restrict__ dis,
                           int* __restrict__ off, int* __restrict__ cur) {
    __shared__ int sums[256];
    int t = threadIdx.x;
    const int seg = (N_NODES + 255) >> 8;  // 40
    int lo = t * seg, hi = lo + seg;
    if (lo > N_NODES) lo = N_NODES;
    if (hi > N_NODES) hi = N_NODES;
    int s = 0;
    for (int i = lo; i < hi; ++i) {
        dis[i] = rsqrtf((float)deg[i] + 1.0f);
        s += deg[i];
    }
    sums[t] = s;
    __syncthreads();
    for (int d = 1; d < 256; d <<= 1) {
        int v = (t >= d) ? sums[t - d] : 0;
        __syncthreads();
        sums[t] += v;
        __syncthreads();
    }
    int run = sums[t] - s;
    for (int i = lo; i < hi; ++i) {
        off[i] = run;
        cur[i] = run;
        run += deg[i];
    }
    if (t == 255) off[N_NODES] = sums[255];
}

__global__ void k_fill(const int* __restrict__ row, const int* __restrict__ col,
                       const float* __restrict__ dis, int* cur,
                       int* __restrict__ crow, float* __restrict__ cnorm) {
    int e = blockIdx.x * 256 + threadIdx.x;
    if (e < N_EDGES) {
        int r = row[e], c = col[e];
        int p = atomicAdd(&cur[c], 1);
        crow[p] = r;
        cnorm[p] = dis[r] * dis[c];
    }
}

// ---------------- all 4 W transposes in one launch: WT[n][k] = bf16(W[k][n]) ------

__global__ void k_transpose(const float* __restrict__ W1, const float* __restrict__ W2,
                            const float* __restrict__ W3, const float* __restrict__ W4,
                            u16* __restrict__ T1, u16* __restrict__ T2,
                            u16* __restrict__ T3, u16* __restrict__ T4) {
    __shared__ u16 tile[32][33];
    int z = blockIdx.z;
    const float* W = (z == 0) ? W1 : (z == 1) ? W2 : (z == 2) ? W3 : W4;
    u16* WT        = (z == 0) ? T1 : (z == 1) ? T2 : (z == 2) ? T3 : T4;
    int K = (z == 0) ? 256 : 512;
    int k0 = blockIdx.y * 32;
    if (k0 >= K) return;
    int n0 = blockIdx.x * 32;
    int tx = threadIdx.x, ty = threadIdx.y;  // (32,8)
    for (int i = 0; i < 32; i += 8)
        tile[ty + i][tx] = f2b(W[(size_t)(k0 + ty + i) * 512 + n0 + tx]);
    __syncthreads();
    for (int i = 0; i < 32; i += 8)
        WT[(size_t)(n0 + ty + i) * K + k0 + tx] = tile[tx][ty + i];
}

// ---------------- agg layer 1: f32 x (C=256) -> bf16 s; one wave/node -------------

__global__ void k_agg_f(const float* __restrict__ in, u16* __restrict__ out,
                        const int* __restrict__ off, const int* __restrict__ crow,
                        const float* __restrict__ cnorm, const float* __restrict__ dis) {
    int node = blockIdx.x * 4 + (threadIdx.x >> 6);
    int lane = threadIdx.x & 63;
    if (node >= N_NODES) return;
    int c = lane * 4;  // C = 256, float4/lane

    float d = dis[node];
    float4 acc = *(const float4*)(in + (size_t)node * 256 + c);
    acc.x *= d * d; acc.y *= d * d; acc.z *= d * d; acc.w *= d * d;
    float4 acc2 = {0.f, 0.f, 0.f, 0.f};

    int b = off[node], e = off[node + 1];
    int i = b;
    for (; i + 1 < e; i += 2) {
        int r0 = crow[i], r1 = crow[i + 1];
        float n0 = cnorm[i], n1 = cnorm[i + 1];
        float4 v0 = *(const float4*)(in + (size_t)r0 * 256 + c);
        float4 v1 = *(const float4*)(in + (size_t)r1 * 256 + c);
        acc.x = fmaf(v0.x, n0, acc.x);  acc2.x = fmaf(v1.x, n1, acc2.x);
        acc.y = fmaf(v0.y, n0, acc.y);  acc2.y = fmaf(v1.y, n1, acc2.y);
        acc.z = fmaf(v0.z, n0, acc.z);  acc2.z = fmaf(v1.z, n1, acc2.z);
        acc.w = fmaf(v0.w, n0, acc.w);  acc2.w = fmaf(v1.w, n1, acc2.w);
    }
    if (i < e) {
        int r0 = crow[i];
        float n0 = cnorm[i];
        float4 v0 = *(const float4*)(in + (size_t)r0 * 256 + c);
        acc.x = fmaf(v0.x, n0, acc.x);
        acc.y = fmaf(v0.y, n0, acc.y);
        acc.z = fmaf(v0.z, n0, acc.z);
        acc.w = fmaf(v0.w, n0, acc.w);
    }
    us4 st;
    st[0] = f2b(acc.x + acc2.x);
    st[1] = f2b(acc.y + acc2.y);
    st[2] = f2b(acc.z + acc2.z);
    st[3] = f2b(acc.w + acc2.w);
    *(us4*)(out + (size_t)node * 256 + c) = st;
}

// ---------------- agg layers 2-4: bf16 h (C=512) -> bf16 s; one wave/node ---------

__global__ void k_agg_b(const u16* __restrict__ in, u16* __restrict__ out,
                        const int* __restrict__ off, const int* __restrict__ crow,
                        const float* __restrict__ cnorm, const float* __restrict__ dis) {
    int node = blockIdx.x * 4 + (threadIdx.x >> 6);
    int lane = threadIdx.x & 63;
    if (node >= N_NODES) return;
    int c = lane * 8;  // C = 512, 8 bf16 = 16B/lane

    float d = dis[node];
    us8 sv = *(const us8*)(in + (size_t)node * 512 + c);
    float acc[8], acc2[8];
#pragma unroll
    for (int j = 0; j < 8; ++j) { acc[j] = b2f(sv[j]) * d * d; acc2[j] = 0.f; }

    int b = off[node], e = off[node + 1];
    int i = b;
    for (; i + 1 < e; i += 2) {
        int r0 = crow[i], r1 = crow[i + 1];
        float n0 = cnorm[i], n1 = cnorm[i + 1];
        us8 v0 = *(const us8*)(in + (size_t)r0 * 512 + c);
        us8 v1 = *(const us8*)(in + (size_t)r1 * 512 + c);
#pragma unroll
        for (int j = 0; j < 8; ++j) {
            acc[j]  = fmaf(b2f(v0[j]), n0, acc[j]);
            acc2[j] = fmaf(b2f(v1[j]), n1, acc2[j]);
        }
    }
    if (i < e) {
        int r0 = crow[i];
        float n0 = cnorm[i];
        us8 v0 = *(const us8*)(in + (size_t)r0 * 512 + c);
#pragma unroll
        for (int j = 0; j < 8; ++j) acc[j] = fmaf(b2f(v0[j]), n0, acc[j]);
    }
    us8 st;
#pragma unroll
    for (int j = 0; j < 8; ++j) st[j] = f2b(acc[j] + acc2[j]);
    *(us8*)(out + (size_t)node * 512 + c) = st;
}

// ---------------- bf16 MFMA GEMM: out = act(A @ W + b) ----------------
// A:[M,K] bf16, BT:[NO,K] bf16, bias f32. OT = u16 (bf16 hidden) or float (d_out).
// 64x64 tile, 4 waves 2x2, 2x2 mfma_f32_16x16x32_bf16. A rows clamped to M-1.

static __device__ __forceinline__ void st_out(float* out, size_t idx, float v) { out[idx] = v; }
static __device__ __forceinline__ void st_out(u16* out, size_t idx, float v) { out[idx] = f2b(v); }

template <typename OT>
__global__ __launch_bounds__(256) void k_gemm(
        const u16* __restrict__ A, const u16* __restrict__ BT,
        const float* __restrict__ bias, OT* __restrict__ out,
        int M, int K, int NO, int relu) {
    int w = threadIdx.x >> 6;
    int lane = threadIdx.x & 63;
    int wm = w >> 1, wn = w & 1;
    int m0 = blockIdx.x * 64 + wm * 32;
    int n0 = blockIdx.y * 64 + wn * 32;
    int l15 = lane & 15;
    int kq = (lane >> 4) * 8;

    int ra0 = m0 + l15;       if (ra0 > M - 1) ra0 = M - 1;
    int ra1 = m0 + 16 + l15;  if (ra1 > M - 1) ra1 = M - 1;

    const u16* a0p = A + (size_t)ra0 * K + kq;
    const u16* a1p = A + (size_t)ra1 * K + kq;
    const u16* b0p = BT + (size_t)(n0 + l15) * K + kq;
    const u16* b1p = b0p + (size_t)16 * K;

    f32x4 acc00 = {0.f, 0.f, 0.f, 0.f};
    f32x4 acc01 = acc00, acc10 = acc00, acc11 = acc00;

    for (int k = 0; k < K; k += 32) {
        s16x8 a0 = *(const s16x8*)(a0p + k);
        s16x8 a1 = *(const s16x8*)(a1p + k);
        s16x8 b0 = *(const s16x8*)(b0p + k);
        s16x8 b1 = *(const s16x8*)(b1p + k);
        acc00 = __builtin_amdgcn_mfma_f32_16x16x32_bf16(a0, b0, acc00, 0, 0, 0);
        acc01 = __builtin_amdgcn_mfma_f32_16x16x32_bf16(a0, b1, acc01, 0, 0, 0);
        acc10 = __builtin_amdgcn_mfma_f32_16x16x32_bf16(a1, b0, acc10, 0, 0, 0);
        acc11 = __builtin_amdgcn_mfma_f32_16x16x32_bf16(a1, b1, acc11, 0, 0, 0);
    }

    // C/D layout: col = lane&15, row = (lane>>4)*4 + r   [m89-verified]
    int r0 = (lane >> 4) * 4;
    float bv0 = bias[n0 + l15];
    float bv1 = bias[n0 + 16 + l15];
#pragma unroll
    for (int r = 0; r < 4; ++r) {
        int row = m0 + r0 + r;
        if (row < M) {
            float v = acc00[r] + bv0;
            if (relu) v = fmaxf(v, 0.f);
            st_out(out, (size_t)row * NO + n0 + l15, v);
            v = acc01[r] + bv1;
            if (relu) v = fmaxf(v, 0.f);
            st_out(out, (size_t)row * NO + n0 + 16 + l15, v);
        }
        int row2 = row + 16;
        if (row2 < M) {
            float v = acc10[r] + bv0;
            if (relu) v = fmaxf(v, 0.f);
            st_out(out, (size_t)row2 * NO + n0 + l15, v);
            v = acc11[r] + bv1;
            if (relu) v = fmaxf(v, 0.f);
            st_out(out, (size_t)row2 * NO + n0 + 16 + l15, v);
        }
    }
}

// ---------------- launch ----------------

extern "C" void kernel_launch(void* const* d_in, const int* in_sizes, int n_in,
                              void* d_out, int out_size, void* d_ws, size_t ws_size,
                              hipStream_t stream) {
    const float* x  = (const float*)d_in[0];
    const int*   ei = (const int*)d_in[1];
    const float* W1 = (const float*)d_in[2];
    const float* b1 = (const float*)d_in[3];
    const float* W2 = (const float*)d_in[4];
    const float* b2 = (const float*)d_in[5];
    const float* W3 = (const float*)d_in[6];
    const float* b3 = (const float*)d_in[7];
    const float* W4 = (const float*)d_in[8];
    const float* b4 = (const float*)d_in[9];

    char* ws = (char*)d_ws;
    size_t o = 0;
    auto alloc = [&](size_t bytes) {
        char* p = ws + o;
        o = (o + bytes + 255) & ~(size_t)255;
        return p;
    };
    int*   row   = (int*)alloc(N_EDGES * 4);
    int*   col   = (int*)alloc(N_EDGES * 4);
    int*   deg   = (int*)alloc(N_NODES * 4);
    float* dis   = (float*)alloc(N_NODES * 4);
    int*   off   = (int*)alloc((N_NODES + 1) * 4);
    int*   cur   = (int*)alloc(N_NODES * 4);
    int*   crow  = (int*)alloc(N_EDGES * 4);
    float* cnorm = (float*)alloc(N_EDGES * 4);
    u16*   WT1   = (u16*)alloc((size_t)512 * 256 * 2);
    u16*   WT2   = (u16*)alloc((size_t)512 * 512 * 2);
    u16*   WT3   = (u16*)alloc((size_t)512 * 512 * 2);
    u16*   WT4   = (u16*)alloc((size_t)512 * 512 * 2);
    u16*   s     = (u16*)alloc((size_t)N_NODES * 512 * 2);  // bf16 aggregated
    u16*   h     = (u16*)alloc((size_t)N_NODES * 512 * 2);  // bf16 hidden
    float* outb  = (float*)d_out;

    dim3 b256(256);
    const int gE = (N_EDGES + 255) / 256;
    const dim3 gG(157, 8);
    const int gA = (N_NODES + 3) / 4;  // one wave/node, 4/block

    k_prep0<<<gE, b256, 0, stream>>>(ei, row, col, deg);
    k_count<<<gE, b256, 0, stream>>>(col, deg);
    k_scan_all<<<1, b256, 0, stream>>>(deg, dis, off, cur);
    k_fill<<<gE, b256, 0, stream>>>(row, col, dis, cur, crow, cnorm);
    k_transpose<<<dim3(16, 16, 4), dim3(32, 8), 0, stream>>>(W1, W2, W3, W4,
                                                             WT1, WT2, WT3, WT4);

    // Layer 1: s = bf16(A_norm @ x), h = bf16(relu(s @ W1 + b1))
    k_agg_f<<<gA, b256, 0, stream>>>(x, s, off, crow, cnorm, dis);
    k_gemm<u16><<<gG, b256, 0, stream>>>(s, WT1, b1, h, N_NODES, 256, 512, 1);
    // Layer 2
    k_agg_b<<<gA, b256, 0, stream>>>(h, s, off, crow, cnorm, dis);
    k_gemm<u16><<<gG, b256, 0, stream>>>(s, WT2, b2, h, N_NODES, 512, 512, 1);
    // Layer 3
    k_agg_b<<<gA, b256, 0, stream>>>(h, s, off, crow, cnorm, dis);
    k_gemm<u16><<<gG, b256, 0, stream>>>(s, WT3, b3, h, N_NODES, 512, 512, 1);
    // Layer 4 (no relu) -> f32 d_out
    k_agg_b<<<gA, b256, 0, stream>>>(h, s, off, crow, cnorm, dis);
    k_gemm<float><<<gG, b256, 0, stream>>>(s, WT4, b4, outb, N_NODES, 512, 512, 0);
}

// Round 11
// 296.257 us; speedup vs baseline: 4.9280x; 1.2708x over previous
//
#include <hip/hip_runtime.h>
#include <hip/hip_bf16.h>

#define N_NODES 10000
#define N_EDGES 160000

typedef __hip_bfloat16 bf16;
typedef unsigned short u16;
typedef float f32x4 __attribute__((ext_vector_type(4)));
typedef short s16x8 __attribute__((ext_vector_type(8)));
typedef unsigned short us8 __attribute__((ext_vector_type(8)));
typedef unsigned short us4 __attribute__((ext_vector_type(4)));

static __device__ __forceinline__ float b2f(u16 u) {
    unsigned v = (unsigned)u << 16;
    return __uint_as_float(v);
}
static __device__ __forceinline__ u16 f2b(float f) {
    bf16 b = __float2bfloat16(f);
    return *reinterpret_cast<u16*>(&b);
}

// async global->LDS, 16B per lane; LDS dest = wave-uniform base + lane*16
#define GLDS(gp, lp)                                                         \
    __builtin_amdgcn_global_load_lds(                                        \
        (const __attribute__((address_space(1))) void*)(const void*)(gp),    \
        (__attribute__((address_space(3))) void*)(lp), 16, 0, 0)

// ---------------- prep 0: zero deg + extract edges (int32/int64 robust) ----------

__global__ void k_prep0(const int* __restrict__ ei,
                        int* __restrict__ row, int* __restrict__ col,
                        int* __restrict__ deg) {
    bool is64 = true;
#pragma unroll
    for (int i = 0; i < 8; ++i) is64 = is64 && (ei[2 * i + 1] == 0);
    int t = blockIdx.x * 256 + threadIdx.x;
    if (t < N_NODES) deg[t] = 0;
    if (t < N_EDGES) {
        if (is64) {
            row[t] = ei[2 * t];
            col[t] = ei[2 * (N_EDGES + t)];
        } else {
            row[t] = ei[t];
            col[t] = ei[N_EDGES + t];
        }
    }
}

__global__ void k_count(const int* __restrict__ col, int* deg) {
    int e = blockIdx.x * 256 + threadIdx.x;
    if (e < N_EDGES) atomicAdd(&deg[col[e]], 1);
}

// Single block: dis = rsqrt(deg+1); exclusive scan of deg -> off, cur.
__global__ void k_scan_all(const int* __restrict__ deg, float* __restrict__ dis,
                           int* __restrict__ off, int* __restrict__ cur) {
    __shared__ int sums[256];
    int t = threadIdx.x;
    const int seg = (N_NODES + 255) >> 8;  // 40
    int lo = t * seg, hi = lo + seg;
    if (lo > N_NODES) lo = N_NODES;
    if (hi > N_NODES) hi = N_NODES;
    int s = 0;
    for (int i = lo; i < hi; ++i) {
        dis[i] = rsqrtf((float)deg[i] + 1.0f);
        s += deg[i];
    }
    sums[t] = s;
    __syncthreads();
    for (int d = 1; d < 256; d <<= 1) {
        int v = (t >= d) ? sums[t - d] : 0;
        __syncthreads();
        sums[t] += v;
        __syncthreads();
    }
    int run = sums[t] - s;
    for (int i = lo; i < hi; ++i) {
        off[i] = run;
        cur[i] = run;
        run += deg[i];
    }
    if (t == 255) off[N_NODES] = sums[255];
}

__global__ void k_fill(const int* __restrict__ row, const int* __restrict__ col,
                       const float* __restrict__ dis, int* cur,
                       int* __restrict__ crow, float* __restrict__ cnorm) {
    int e = blockIdx.x * 256 + threadIdx.x;
    if (e < N_EDGES) {
        int r = row[e], c = col[e];
        int p = atomicAdd(&cur[c], 1);
        crow[p] = r;
        cnorm[p] = dis[r] * dis[c];
    }
}

// ---------------- x f32 -> bf16 (layer-1 gather then reads 8B/lane) ---------------

__global__ void k_convx(const float* __restrict__ x, u16* __restrict__ xb) {
    int i = blockIdx.x * 256 + threadIdx.x;  // covers N_NODES*256/4 = 640000
    float4 v = *(const float4*)(x + (size_t)i * 4);
    us4 st;
    st[0] = f2b(v.x); st[1] = f2b(v.y); st[2] = f2b(v.z); st[3] = f2b(v.w);
    *(us4*)(xb + (size_t)i * 4) = st;
}

// ---------------- all 4 W transposes in one launch: WT[n][k] = bf16(W[k][n]) ------

__global__ void k_transpose(const float* __restrict__ W1, const float* __restrict__ W2,
                            const float* __restrict__ W3, const float* __restrict__ W4,
                            u16* __restrict__ T1, u16* __restrict__ T2,
                            u16* __restrict__ T3, u16* __restrict__ T4) {
    __shared__ u16 tile[32][33];
    int z = blockIdx.z;
    const float* W = (z == 0) ? W1 : (z == 1) ? W2 : (z == 2) ? W3 : W4;
    u16* WT        = (z == 0) ? T1 : (z == 1) ? T2 : (z == 2) ? T3 : T4;
    int K = (z == 0) ? 256 : 512;
    int k0 = blockIdx.y * 32;
    if (k0 >= K) return;
    int n0 = blockIdx.x * 32;
    int tx = threadIdx.x, ty = threadIdx.y;  // (32,8)
    for (int i = 0; i < 32; i += 8)
        tile[ty + i][tx] = f2b(W[(size_t)(k0 + ty + i) * 512 + n0 + tx]);
    __syncthreads();
    for (int i = 0; i < 32; i += 8)
        WT[(size_t)(n0 + ty + i) * K + k0 + tx] = tile[tx][ty + i];
}

// ---------------- CSR-gather aggregation, bf16 in/out, f32 accumulate -------------
// One wave per node; CE bf16 elems per lane (C = CE*64). Self-loop fused.

template <int CE> struct VecT;
template <> struct VecT<4> { typedef us4 T; };
template <> struct VecT<8> { typedef us8 T; };

template <int CE>
__global__ void k_agg(const u16* __restrict__ in, u16* __restrict__ out,
                      const int* __restrict__ off, const int* __restrict__ crow,
                      const float* __restrict__ cnorm, const float* __restrict__ dis) {
    typedef typename VecT<CE>::T VT;
    const int C = CE * 64;
    int node = blockIdx.x * 4 + (threadIdx.x >> 6);
    int lane = threadIdx.x & 63;
    if (node >= N_NODES) return;
    int c = lane * CE;

    float d = dis[node];
    VT sv = *(const VT*)(in + (size_t)node * C + c);
    float acc[CE], acc2[CE];
#pragma unroll
    for (int j = 0; j < CE; ++j) { acc[j] = b2f(sv[j]) * d * d; acc2[j] = 0.f; }

    int b = off[node], e = off[node + 1];
    int i = b;
    for (; i + 1 < e; i += 2) {
        int r0 = crow[i], r1 = crow[i + 1];
        float n0 = cnorm[i], n1 = cnorm[i + 1];
        VT v0 = *(const VT*)(in + (size_t)r0 * C + c);
        VT v1 = *(const VT*)(in + (size_t)r1 * C + c);
#pragma unroll
        for (int j = 0; j < CE; ++j) {
            acc[j]  = fmaf(b2f(v0[j]), n0, acc[j]);
            acc2[j] = fmaf(b2f(v1[j]), n1, acc2[j]);
        }
    }
    if (i < e) {
        int r0 = crow[i];
        float n0 = cnorm[i];
        VT v0 = *(const VT*)(in + (size_t)r0 * C + c);
#pragma unroll
        for (int j = 0; j < CE; ++j) acc[j] = fmaf(b2f(v0[j]), n0, acc[j]);
    }
    VT st;
#pragma unroll
    for (int j = 0; j < CE; ++j) st[j] = f2b(acc[j] + acc2[j]);
    *(VT*)(out + (size_t)node * C + c) = st;
}

// ---------------- LDS-staged bf16 MFMA GEMM: out = act(A @ W + b) -----------------
// A:[M,K] bf16, BT:[NO,K] bf16, bias f32. 64x64 tile, 4 waves 2x2, wave 32x32.
// BK=64 as two 32-k panels (64B LDS rows -> 2-way bank aliasing = free).
// Staging via global_load_lds width 16. A rows clamped to M-1 (store-guarded).

static __device__ __forceinline__ void st_out(float* out, size_t idx, float v) { out[idx] = v; }
static __device__ __forceinline__ void st_out(u16* out, size_t idx, float v) { out[idx] = f2b(v); }

template <typename OT>
__global__ __launch_bounds__(256) void k_gemm(
        const u16* __restrict__ A, const u16* __restrict__ BT,
        const float* __restrict__ bias, OT* __restrict__ out,
        int M, int K, int NO, int relu) {
    __shared__ u16 As[2][64][32];  // [panel][m][k]  rows 64B
    __shared__ u16 Bs[2][64][32];  // [panel][n][k]

    int tid = threadIdx.x;
    int w = tid >> 6;
    int lane = tid & 63;
    int wm = w >> 1, wn = w & 1;
    int m0 = blockIdx.x * 64;
    int n0 = blockIdx.y * 64;
    int l15 = lane & 15;
    int kq = lane >> 4;  // 0..3

    // staging: wave w stages panel (w&1), rows (w>>1)*32 + {0,16} of both A and B
    int sp  = w & 1;
    int srb = (w >> 1) * 32;
    int srow = lane >> 2;         // 0..15
    int skc  = (lane & 3) * 8;    // k elems within 32-panel

    int ar0 = m0 + srb + srow;      if (ar0 > M - 1) ar0 = M - 1;
    int ar1 = m0 + srb + 16 + srow; if (ar1 > M - 1) ar1 = M - 1;
    int br0 = n0 + srb + srow;
    int br1 = br0 + 16;
    const u16* agp0 = A + (size_t)ar0 * K + sp * 32 + skc;
    const u16* agp1 = A + (size_t)ar1 * K + sp * 32 + skc;
    const u16* bgp0 = BT + (size_t)br0 * K + sp * 32 + skc;
    const u16* bgp1 = BT + (size_t)br1 * K + sp * 32 + skc;
    u16* al0 = &As[sp][srb][0];        // wave-uniform LDS bases
    u16* al1 = &As[sp][srb + 16][0];
    u16* bl0 = &Bs[sp][srb][0];
    u16* bl1 = &Bs[sp][srb + 16][0];

    int aRow0 = wm * 32 + l15, aRow1 = aRow0 + 16;
    int bRow0 = wn * 32 + l15, bRow1 = bRow0 + 16;

    f32x4 acc00 = {0.f, 0.f, 0.f, 0.f};
    f32x4 acc01 = acc00, acc10 = acc00, acc11 = acc00;

    for (int k0 = 0; k0 < K; k0 += 64) {
        GLDS(agp0 + k0, al0);
        GLDS(agp1 + k0, al1);
        GLDS(bgp0 + k0, bl0);
        GLDS(bgp1 + k0, bl1);
        __syncthreads();  // compiler drains vmcnt before s_barrier
#pragma unroll
        for (int p = 0; p < 2; ++p) {
            s16x8 a0 = *(const s16x8*)&As[p][aRow0][kq * 8];
            s16x8 a1 = *(const s16x8*)&As[p][aRow1][kq * 8];
            s16x8 b0 = *(const s16x8*)&Bs[p][bRow0][kq * 8];
            s16x8 b1 = *(const s16x8*)&Bs[p][bRow1][kq * 8];
            acc00 = __builtin_amdgcn_mfma_f32_16x16x32_bf16(a0, b0, acc00, 0, 0, 0);
            acc01 = __builtin_amdgcn_mfma_f32_16x16x32_bf16(a0, b1, acc01, 0, 0, 0);
            acc10 = __builtin_amdgcn_mfma_f32_16x16x32_bf16(a1, b0, acc10, 0, 0, 0);
            acc11 = __builtin_amdgcn_mfma_f32_16x16x32_bf16(a1, b1, acc11, 0, 0, 0);
        }
        __syncthreads();
    }

    // C/D layout: col = lane&15, row = (lane>>4)*4 + r   [m89-verified]
    int r0 = (lane >> 4) * 4;
    int cm0 = m0 + wm * 32;
    int cn0 = n0 + wn * 32;
    float bv0 = bias[cn0 + l15];
    float bv1 = bias[cn0 + 16 + l15];
#pragma unroll
    for (int r = 0; r < 4; ++r) {
        int rowa = cm0 + r0 + r;
        if (rowa < M) {
            float v = acc00[r] + bv0;
            if (relu) v = fmaxf(v, 0.f);
            st_out(out, (size_t)rowa * NO + cn0 + l15, v);
            v = acc01[r] + bv1;
            if (relu) v = fmaxf(v, 0.f);
            st_out(out, (size_t)rowa * NO + cn0 + 16 + l15, v);
        }
        int rowb = rowa + 16;
        if (rowb < M) {
            float v = acc10[r] + bv0;
            if (relu) v = fmaxf(v, 0.f);
            st_out(out, (size_t)rowb * NO + cn0 + l15, v);
            v = acc11[r] + bv1;
            if (relu) v = fmaxf(v, 0.f);
            st_out(out, (size_t)rowb * NO + cn0 + 16 + l15, v);
        }
    }
}

// ---------------- launch ----------------

extern "C" void kernel_launch(void* const* d_in, const int* in_sizes, int n_in,
                              void* d_out, int out_size, void* d_ws, size_t ws_size,
                              hipStream_t stream) {
    const float* x  = (const float*)d_in[0];
    const int*   ei = (const int*)d_in[1];
    const float* W1 = (const float*)d_in[2];
    const float* b1 = (const float*)d_in[3];
    const float* W2 = (const float*)d_in[4];
    const float* b2 = (const float*)d_in[5];
    const float* W3 = (const float*)d_in[6];
    const float* b3 = (const float*)d_in[7];
    const float* W4 = (const float*)d_in[8];
    const float* b4 = (const float*)d_in[9];

    char* ws = (char*)d_ws;
    size_t o = 0;
    auto alloc = [&](size_t bytes) {
        char* p = ws + o;
        o = (o + bytes + 255) & ~(size_t)255;
        return p;
    };
    int*   row   = (int*)alloc(N_EDGES * 4);
    int*   col   = (int*)alloc(N_EDGES * 4);
    int*   deg   = (int*)alloc(N_NODES * 4);
    float* dis   = (float*)alloc(N_NODES * 4);
    int*   off   = (int*)alloc((N_NODES + 1) * 4);
    int*   cur   = (int*)alloc(N_NODES * 4);
    int*   crow  = (int*)alloc(N_EDGES * 4);
    float* cnorm = (float*)alloc(N_EDGES * 4);
    u16*   WT1   = (u16*)alloc((size_t)512 * 256 * 2);
    u16*   WT2   = (u16*)alloc((size_t)512 * 512 * 2);
    u16*   WT3   = (u16*)alloc((size_t)512 * 512 * 2);
    u16*   WT4   = (u16*)alloc((size_t)512 * 512 * 2);
    u16*   xb    = (u16*)alloc((size_t)N_NODES * 256 * 2);  // bf16 x
    u16*   s     = (u16*)alloc((size_t)N_NODES * 512 * 2);  // bf16 aggregated
    u16*   h     = (u16*)alloc((size_t)N_NODES * 512 * 2);  // bf16 hidden
    float* outb  = (float*)d_out;

    dim3 b256(256);
    const int gE = (N_EDGES + 255) / 256;
    const dim3 gG(157, 8);             // 64x64 tiles: 1256 blocks
    const int gA = (N_NODES + 3) / 4;  // one wave/node

    k_prep0<<<gE, b256, 0, stream>>>(ei, row, col, deg);
    k_count<<<gE, b256, 0, stream>>>(col, deg);
    k_scan_all<<<1, b256, 0, stream>>>(deg, dis, off, cur);
    k_fill<<<gE, b256, 0, stream>>>(row, col, dis, cur, crow, cnorm);
    k_convx<<<N_NODES * 256 / 4 / 256, b256, 0, stream>>>(x, xb);
    k_transpose<<<dim3(16, 16, 4), dim3(32, 8), 0, stream>>>(W1, W2, W3, W4,
                                                             WT1, WT2, WT3, WT4);

    // Layer 1: s = bf16(A_norm @ x) [C=256], h = bf16(relu(s @ W1 + b1))
    k_agg<4><<<gA, b256, 0, stream>>>(xb, s, off, crow, cnorm, dis);
    k_gemm<u16><<<gG, b256, 0, stream>>>(s, WT1, b1, h, N_NODES, 256, 512, 1);
    // Layer 2
    k_agg<8><<<gA, b256, 0, stream>>>(h, s, off, crow, cnorm, dis);
    k_gemm<u16><<<gG, b256, 0, stream>>>(s, WT2, b2, h, N_NODES, 512, 512, 1);
    // Layer 3
    k_agg<8><<<gA, b256, 0, stream>>>(h, s, off, crow, cnorm, dis);
    k_gemm<u16><<<gG, b256, 0, stream>>>(s, WT3, b3, h, N_NODES, 512, 512, 1);
    // Layer 4 (no relu) -> f32 d_out
    k_agg<8><<<gA, b256, 0, stream>>>(h, s, off, crow, cnorm, dis);
    k_gemm<float><<<gG, b256, 0, stream>>>(s, WT4, b4, outb, N_NODES, 512, 512, 0);
}